// Round 5
// baseline (264.596 us; speedup 1.0000x reference)
//
#include <hip/hip_runtime.h>

// Conv2D 15x15 valid, 4096^2 fp32 -> 4082^2 fp32, bf16-MFMA Toeplitz band.
// Round 5: x-marching pipelined strips. Single-shot blocks (r2/r4) plateau at
// 75-80 us with every pipe <25% busy: stage->barrier->compute in generational
// lockstep. This kernel gives each block a 4-step steady-state loop over a
// 32-row x 768-col strip: per 192-col step, register-prefetch step s+1's
// 46x208 fp32 chunk, MFMA-compute step s from the bf16 double buffer, then
// cvt+ds_write the prefetch, one barrier. HBM latency rides under compute.
//
// 512 thr = 8 waves; wave = (rb = wv&1: 16 rows, cp = wv>>1: 48 cols).
// Per wave per step: 15 kh x 3 t = 45 v_mfma_f32_16x16x32_bf16, each fed by
// one ds_read_b128 off a single base + imm offset. B band (15 x bf16x8,
// B[k][n]=w[kh][k-n]) in 60 VGPRs for the whole block. LDS: 2 x 46x216
// shorts = 38.8 KB -> 2 blocks/CU; __launch_bounds__(512,4) caps VGPR at 128.

#define HIN 4096
#define WIN 4096
#define KH 15
#define KW 15
#define OH (HIN - KH + 1)  // 4082
#define OW (WIN - KW + 1)  // 4082

#define BAND 32                    // output rows per block
#define SROWS (BAND + KH - 1)      // 46 staged rows
#define STEPC 192                  // output cols per step
#define NSTEP 4
#define STRIPC (STEPC * NSTEP)     // 768
#define SCOLS 208                  // staged cols per step (192 + 14 -> pad 208)
#define LDSW 216                   // bf16 row stride (432 B; 108 dw = 12 mod 32 skew)
#define BUFSH (SROWS * LDSW)       // 9936 shorts per buffer
#define SLOTS (SROWS * (SCOLS / 4))  // 2392 float4 staging slots
#define NPF 5                      // ceil(2392/512)

typedef short bf16x8 __attribute__((ext_vector_type(8)));
typedef float f32x4  __attribute__((ext_vector_type(4)));

static __device__ inline short f2bf(float f) {  // fp32 -> bf16 RNE
    unsigned u = __float_as_uint(f);
    u += 0x7fffu + ((u >> 16) & 1u);
    return (short)(u >> 16);
}

static __device__ inline float4 load_clamped(const float* __restrict__ x,
                                             int gy, int gx) {
    if (gy > HIN - 1) gy = HIN - 1;
    if (gx + 3 <= WIN - 1) {
        return *reinterpret_cast<const float4*>(&x[(size_t)gy * WIN + gx]);
    }
    const float* row = &x[(size_t)gy * WIN];
    const int x0 = (gx + 0 > WIN - 1) ? WIN - 1 : gx + 0;
    const int x1 = (gx + 1 > WIN - 1) ? WIN - 1 : gx + 1;
    const int x2 = (gx + 2 > WIN - 1) ? WIN - 1 : gx + 2;
    const int x3 = (gx + 3 > WIN - 1) ? WIN - 1 : gx + 3;
    return make_float4(row[x0], row[x1], row[x2], row[x3]);
}

__global__ __launch_bounds__(512, 4)
void conv2d_mfma_strip(const float* __restrict__ x,
                       const float* __restrict__ w,
                       const float* __restrict__ bias,
                       float* __restrict__ out) {
    __shared__ short lds[2 * BUFSH];   // 39744 B

    const int tid  = threadIdx.x;
    const int lane = tid & 63;
    const int wv   = tid >> 6;
    const int m    = lane & 15;
    const int q    = lane >> 4;
    const int rb   = wv & 1;           // 16-row sub-band
    const int cp   = wv >> 1;          // 48-col group
    const int row0 = blockIdx.x * BAND;          // band: consecutive blocks share halo rows (L2)
    const int cbase = blockIdx.y * STRIPC;       // strip start col

    // ---- B fragments, per-lane from global w (L1-resident 900 B) ----
    // 16x16x32 B-op layout: lane holds B[k=q*8+j][n=m]; B[k][n]=w[kh][k-n].
    bf16x8 B[KH];
#pragma unroll
    for (int kh = 0; kh < KH; ++kh) {
#pragma unroll
        for (int j = 0; j < 8; ++j) {
            const int d = q * 8 + j - m;
            B[kh][j] = (d >= 0 && d < KW) ? f2bf(w[kh * KW + d]) : (short)0;
        }
    }
    const float b0 = bias[0];

    // ---- stage step 0 into buf0 ----
#pragma unroll
    for (int i = 0; i < NPF; ++i) {
        const int f = tid + i * 512;
        if (f < SLOTS) {
            const int r  = f / (SCOLS / 4);
            const int c4 = (f - r * (SCOLS / 4)) * 4;
            const float4 v = load_clamped(x, row0 + r, cbase + c4);
            short4 s;
            s.x = f2bf(v.x); s.y = f2bf(v.y); s.z = f2bf(v.z); s.w = f2bf(v.w);
            *reinterpret_cast<short4*>(&lds[r * LDSW + c4]) = s;
        }
    }
    __syncthreads();

    for (int s = 0; s < NSTEP; ++s) {
        const short* cur = &lds[(s & 1) * BUFSH];
        short*       nxt = &lds[((s + 1) & 1) * BUFSH];
        const int    c0  = cbase + s * STEPC;
        const bool   pfn = (s + 1 < NSTEP) && (c0 + STEPC < OW);

        // -- issue global prefetch for step s+1 (hidden under compute) --
        float4 pf[NPF];
        if (pfn) {
#pragma unroll
            for (int i = 0; i < NPF; ++i) {
                const int f = tid + i * 512;
                if (f < SLOTS) {
                    const int r  = f / (SCOLS / 4);
                    const int c4 = (f - r * (SCOLS / 4)) * 4;
                    pf[i] = load_clamped(x, row0 + r, c0 + STEPC + c4);
                }
            }
        }

        if (c0 < OW) {   // uniform: skip fully-OOB steps (last strip)
            // -- compute: 15 kh x 3 col-tiles of 16x16x32 MFMA --
            f32x4 acc[3];
#pragma unroll
            for (int t = 0; t < 3; ++t) acc[t] = (f32x4){0.f, 0.f, 0.f, 0.f};

            const short* abase = cur + (rb * 16 + m) * LDSW + cp * 48 + q * 8;
#pragma unroll
            for (int kh = 0; kh < KH; ++kh) {
#pragma unroll
                for (int t = 0; t < 3; ++t) {
                    const bf16x8 a = *reinterpret_cast<const bf16x8*>(
                        abase + kh * LDSW + t * 16);              // ds_read_b128
                    acc[t] = __builtin_amdgcn_mfma_f32_16x16x32_bf16(a, B[kh], acc[t], 0, 0, 0);
                }
            }

            // -- store: D layout col=lane&15, row=(lane>>4)*4+reg --
            const int orow0 = row0 + rb * 16 + q * 4;
#pragma unroll
            for (int t = 0; t < 3; ++t) {
                const int col = c0 + cp * 48 + t * 16 + m;
                if (col < OW) {
#pragma unroll
                    for (int r = 0; r < 4; ++r) {
                        const int row = orow0 + r;
                        if (row < OH)
                            out[(size_t)row * OW + col] = acc[t][r] + b0;
                    }
                }
            }
        }

        // -- cvt + LDS-write prefetch into back buffer --
        if (pfn) {
#pragma unroll
            for (int i = 0; i < NPF; ++i) {
                const int f = tid + i * 512;
                if (f < SLOTS) {
                    const int r  = f / (SCOLS / 4);
                    const int c4 = (f - r * (SCOLS / 4)) * 4;
                    short4 sv;
                    sv.x = f2bf(pf[i].x); sv.y = f2bf(pf[i].y);
                    sv.z = f2bf(pf[i].z); sv.w = f2bf(pf[i].w);
                    *reinterpret_cast<short4*>(&nxt[r * LDSW + c4]) = sv;
                }
            }
        }
        __syncthreads();
    }
}

extern "C" void kernel_launch(void* const* d_in, const int* in_sizes, int n_in,
                              void* d_out, int out_size, void* d_ws, size_t ws_size,
                              hipStream_t stream) {
    const float* x    = (const float*)d_in[0];
    const float* w    = (const float*)d_in[1];
    const float* bias = (const float*)d_in[2];
    float* out        = (float*)d_out;

    dim3 grid((OH + BAND - 1) / BAND, (OW + STRIPC - 1) / STRIPC);  // 128 x 6
    dim3 block(512);
    conv2d_mfma_strip<<<grid, block, 0, stream>>>(x, w, bias, out);
}